// Round 1
// baseline (80.690 us; speedup 1.0000x reference)
//
#include <hip/hip_runtime.h>

#define NBINS 1536            // 2 * 24 * 32
#define NSUB  4               // one LDS sub-histogram per wave (256 threads = 4 waves)
#define HIST_BLOCKS 1024
#define HIST_THREADS 256

__global__ void zero_hist_kernel(unsigned int* __restrict__ g) {
    int i = blockIdx.x * blockDim.x + threadIdx.x;
    if (i < NBINS) g[i] = 0u;
}

__global__ __launch_bounds__(HIST_THREADS)
void event_hist_kernel(const float4* __restrict__ ev, unsigned int* __restrict__ g, int n) {
    __shared__ unsigned int lh[NSUB * NBINS];   // 24 KiB
    for (int i = threadIdx.x; i < NSUB * NBINS; i += HIST_THREADS) lh[i] = 0u;
    __syncthreads();

    unsigned int* mysub = &lh[(threadIdx.x >> 6) * NBINS];  // per-wave histogram
    const int stride = gridDim.x * HIST_THREADS;
    for (int i = blockIdx.x * HIST_THREADS + threadIdx.x; i < n; i += stride) {
        float4 e = ev[i];
        // replicate ref bit-exactly: f32 mul by BINS/SENSOR, trunc toward zero, clip
        int xb = (int)(e.x * (32.0f / 640.0f));
        int yb = (int)(e.y * (24.0f / 480.0f));
        xb = min(max(xb, 0), 31);
        yb = min(max(yb, 0), 23);
        int p = (e.w > 0.0f) ? 0 : 768;         // pol channel offset (768 = 24*32)
        atomicAdd(&mysub[p + (yb << 5) + xb], 1u);
    }
    __syncthreads();

    // flush block-local sums to the global histogram
    for (int i = threadIdx.x; i < NBINS; i += HIST_THREADS) {
        unsigned int s = lh[i] + lh[NBINS + i] + lh[2 * NBINS + i] + lh[3 * NBINS + i];
        atomicAdd(&g[i], s);
    }
}

__global__ void normalize_kernel(const unsigned int* __restrict__ g,
                                 float* __restrict__ out, float total) {
    int i = blockIdx.x * blockDim.x + threadIdx.x;
    if (i < NBINS) out[i] = (float)g[i] / total;  // counts exact ints; total=20M exact in f32
}

extern "C" void kernel_launch(void* const* d_in, const int* in_sizes, int n_in,
                              void* d_out, int out_size, void* d_ws, size_t ws_size,
                              hipStream_t stream) {
    const float4* ev = (const float4*)d_in[0];   // events [N,4] row-major -> one float4/event
    const int n = in_sizes[0] / 4;
    unsigned int* g = (unsigned int*)d_ws;       // 6 KiB of workspace
    float* out = (float*)d_out;

    zero_hist_kernel<<<(NBINS + 255) / 256, 256, 0, stream>>>(g);
    event_hist_kernel<<<HIST_BLOCKS, HIST_THREADS, 0, stream>>>(ev, g, n);
    normalize_kernel<<<(NBINS + 255) / 256, 256, 0, stream>>>(g, out, (float)n);
}